// Round 1
// baseline (1169.356 us; speedup 1.0000x reference)
//
#include <hip/hip_runtime.h>

#define DIM 128
#define NEG 0.2f

__device__ __forceinline__ float lrelu(float v) { return v > 0.f ? v : NEG * v; }

// ---------------- GEMM: H = X @ W  (X: [N,128], W: [128,128]) ----------------
// Block: 256 threads, tile 64 rows x 128 cols, full K=128.
// Thread t: cols c0..c0+3 (c0=(t&31)*4), rows rg..rg+7 (rg=(t>>5)*8).
__global__ __launch_bounds__(256) void gemm128(const float* __restrict__ X,
                                               const float* __restrict__ W,
                                               float* __restrict__ H, int N) {
    __shared__ float sx[64 * 128];
    const int t = threadIdx.x;
    const int r0g = blockIdx.x * 64;
    const int remRows = N - r0g;

    // stage X tile (2048 float4s, 8 per thread)
    const float4* X4 = (const float4*)(X + (size_t)r0g * DIM);
    float4* sx4 = (float4*)sx;
#pragma unroll
    for (int i = 0; i < 8; ++i) {
        int f = t + i * 256;      // float4 index in tile
        int row = f >> 5;         // 32 float4 per row
        float4 v = make_float4(0.f, 0.f, 0.f, 0.f);
        if (row < remRows) v = X4[f];
        sx4[f] = v;
    }
    __syncthreads();

    const int c0 = (t & 31) * 4;
    const int rg = (t >> 5) * 8;
    float acc[8][4];
#pragma unroll
    for (int i = 0; i < 8; ++i)
#pragma unroll
        for (int j = 0; j < 4; ++j) acc[i][j] = 0.f;

    const float* Wp = W + c0;
    for (int k = 0; k < 128; k += 4) {
        float4 w0 = *(const float4*)(Wp + (k + 0) * DIM);
        float4 w1 = *(const float4*)(Wp + (k + 1) * DIM);
        float4 w2 = *(const float4*)(Wp + (k + 2) * DIM);
        float4 w3 = *(const float4*)(Wp + (k + 3) * DIM);
#pragma unroll
        for (int i = 0; i < 8; ++i) {
            float4 a = *(const float4*)(sx + (rg + i) * 128 + k);
            acc[i][0] += a.x * w0.x; acc[i][1] += a.x * w0.y; acc[i][2] += a.x * w0.z; acc[i][3] += a.x * w0.w;
            acc[i][0] += a.y * w1.x; acc[i][1] += a.y * w1.y; acc[i][2] += a.y * w1.z; acc[i][3] += a.y * w1.w;
            acc[i][0] += a.z * w2.x; acc[i][1] += a.z * w2.y; acc[i][2] += a.z * w2.z; acc[i][3] += a.z * w2.w;
            acc[i][0] += a.w * w3.x; acc[i][1] += a.w * w3.y; acc[i][2] += a.w * w3.z; acc[i][3] += a.w * w3.w;
        }
    }

#pragma unroll
    for (int i = 0; i < 8; ++i) {
        int row = rg + i;
        if (row < remRows) {
            float4 o = make_float4(acc[i][0], acc[i][1], acc[i][2], acc[i][3]);
            *(float4*)(H + (size_t)(r0g + row) * DIM + c0) = o;
        }
    }
}

// ---------------- per-node attention logits: al = h@a_src, ar = h@a_dst -----
__global__ __launch_bounds__(256) void alar_kernel(const float* __restrict__ H,
                                                   const float* __restrict__ asrc,
                                                   const float* __restrict__ adst,
                                                   float* __restrict__ al,
                                                   float* __restrict__ ar, int N) {
    int w = blockIdx.x * 4 + (threadIdx.x >> 6);
    int lane = threadIdx.x & 63;
    if (w >= N) return;
    const float* hp = H + (size_t)w * DIM;
    float h0 = hp[lane], h1 = hp[lane + 64];
    float pa = h0 * asrc[lane] + h1 * asrc[lane + 64];
    float pr = h0 * adst[lane] + h1 * adst[lane + 64];
#pragma unroll
    for (int off = 32; off; off >>= 1) {
        pa += __shfl_down(pa, off);
        pr += __shfl_down(pr, off);
    }
    if (lane == 0) { al[w] = pa; ar[w] = pr; }
}

// ---------------- CSR build helpers ----------------
__global__ void hist_kernel(const int* __restrict__ dst, int* __restrict__ cnt, int E) {
    int e = blockIdx.x * blockDim.x + threadIdx.x;
    if (e < E) atomicAdd(&cnt[dst[e]], 1);
}

__global__ __launch_bounds__(1024) void scan_kernel(const int* __restrict__ cnt,
                                                    int* __restrict__ row_off,
                                                    int* __restrict__ cursor, int N) {
    __shared__ int sd[1024];
    __shared__ int run;
    int t = threadIdx.x;
    if (t == 0) run = 0;
    __syncthreads();
    for (int base = 0; base < N; base += 1024) {
        int i = base + t;
        int v = (i < N) ? cnt[i] : 0;
        sd[t] = v;
        __syncthreads();
        for (int st = 1; st < 1024; st <<= 1) {
            int add = (t >= st) ? sd[t - st] : 0;
            __syncthreads();
            sd[t] += add;
            __syncthreads();
        }
        int excl = run + sd[t] - v;
        if (i < N) { row_off[i] = excl; cursor[i] = excl; }
        int total = sd[1023];
        __syncthreads();
        if (t == 0) run += total;
        __syncthreads();
    }
    if (t == 0) row_off[N] = run;
}

__global__ void scatter_kernel(const int* __restrict__ src, const int* __restrict__ dst,
                               int* __restrict__ cursor, int* __restrict__ col, int E) {
    int e = blockIdx.x * blockDim.x + threadIdx.x;
    if (e < E) {
        int d = dst[e];
        int p = atomicAdd(&cursor[d], 1);
        col[p] = src[e];
    }
}

// ---------------- fused softmax-by-dst + aggregation, one wave per node -----
// lane covers dims [2*lane, 2*lane+1] (float2).
__global__ __launch_bounds__(256) void agg_kernel(const float* __restrict__ H,
                                                  const float* __restrict__ al,
                                                  const float* __restrict__ ar,
                                                  const int* __restrict__ row_off,
                                                  const int* __restrict__ col,
                                                  const float* __restrict__ bias,
                                                  float* __restrict__ out, int N, int relu) {
    int w = blockIdx.x * 4 + (threadIdx.x >> 6);
    int lane = threadIdx.x & 63;
    if (w >= N) return;

    int beg = row_off[w], end = row_off[w + 1];
    float arn = ar[w];
    float vself = lrelu(al[w] + arn);

    // phase 1: segment max (incl. self loop)
    float mloc = vself;
    for (int e = beg + lane; e < end; e += 64) {
        mloc = fmaxf(mloc, lrelu(al[col[e]] + arn));
    }
#pragma unroll
    for (int off = 32; off; off >>= 1) mloc = fmaxf(mloc, __shfl_xor(mloc, off));
    const float m = mloc;

    // phase 2: segment sum of exp
    float sloc = 0.f;
    for (int e = beg + lane; e < end; e += 64) {
        sloc += __expf(lrelu(al[col[e]] + arn) - m);
    }
#pragma unroll
    for (int off = 32; off; off >>= 1) sloc += __shfl_xor(sloc, off);
    const float s = sloc + __expf(vself - m);
    const float invs = 1.f / s;

    // phase 3: weighted aggregation (wave-wide per edge)
    float aself = __expf(vself - m) * invs;
    const float* hw = H + (size_t)w * DIM;
    float2 hs2 = *(const float2*)(hw + 2 * lane);
    float acc0 = aself * hs2.x;
    float acc1 = aself * hs2.y;
    for (int e = beg; e < end; ++e) {
        int sn = col[e];
        float alpha = __expf(lrelu(al[sn] + arn) - m) * invs;
        float2 hv = *(const float2*)(H + (size_t)sn * DIM + 2 * lane);
        acc0 += alpha * hv.x;
        acc1 += alpha * hv.y;
    }

    float2 b2 = *(const float2*)(bias + 2 * lane);
    float o0 = acc0 + b2.x;
    float o1 = acc1 + b2.y;
    if (relu) { o0 = fmaxf(o0, 0.f); o1 = fmaxf(o1, 0.f); }
    *(float2*)(out + (size_t)w * DIM + 2 * lane) = make_float2(o0, o1);
}

// ---------------- host-side launch ----------------
extern "C" void kernel_launch(void* const* d_in, const int* in_sizes, int n_in,
                              void* d_out, int out_size, void* d_ws, size_t ws_size,
                              hipStream_t stream) {
    const float* x = (const float*)d_in[0];
    const float* W[5];
    const float* asv[5];
    const float* adv[5];
    const float* bv[5];
    for (int i = 0; i < 5; ++i) {
        W[i]   = (const float*)d_in[1 + 4 * i];
        asv[i] = (const float*)d_in[2 + 4 * i];
        adv[i] = (const float*)d_in[3 + 4 * i];
        bv[i]  = (const float*)d_in[4 + 4 * i];
    }
    const int* ei  = (const int*)d_in[21];
    const int* eix = (const int*)d_in[22];
    const int N  = in_sizes[0] / DIM;
    const int E1 = in_sizes[21] / 2;
    const int E2 = in_sizes[22] / 2;

    // workspace layout
    size_t off = 0;
    auto alloc = [&](size_t bytes) {
        void* r = (char*)d_ws + off;
        off += (bytes + 255) & ~(size_t)255;
        return r;
    };
    float* Hbuf = (float*)alloc((size_t)N * DIM * sizeof(float));
    float* al   = (float*)alloc((size_t)N * sizeof(float));
    float* ar   = (float*)alloc((size_t)N * sizeof(float));
    int* cnt    = (int*)alloc((size_t)N * sizeof(int));
    int* cur    = (int*)alloc((size_t)N * sizeof(int));
    int* ro1    = (int*)alloc((size_t)(N + 1) * sizeof(int));
    int* col1   = (int*)alloc((size_t)E1 * sizeof(int));
    int* ro2    = (int*)alloc((size_t)(N + 1) * sizeof(int));
    int* col2   = (int*)alloc((size_t)E2 * sizeof(int));
    (void)ws_size;

    float* F = (float*)d_out;  // feature ping-pong lives in d_out

    // build CSR (by dst) for both edge sets
    {
        const int* src = ei;
        const int* dst = ei + E1;
        hipMemsetAsync(cnt, 0, (size_t)N * sizeof(int), stream);
        hist_kernel<<<(E1 + 255) / 256, 256, 0, stream>>>(dst, cnt, E1);
        scan_kernel<<<1, 1024, 0, stream>>>(cnt, ro1, cur, N);
        scatter_kernel<<<(E1 + 255) / 256, 256, 0, stream>>>(src, dst, cur, col1, E1);
    }
    {
        const int* src = eix;
        const int* dst = eix + E2;
        hipMemsetAsync(cnt, 0, (size_t)N * sizeof(int), stream);
        hist_kernel<<<(E2 + 255) / 256, 256, 0, stream>>>(dst, cnt, E2);
        scan_kernel<<<1, 1024, 0, stream>>>(cnt, ro2, cur, N);
        scatter_kernel<<<(E2 + 255) / 256, 256, 0, stream>>>(src, dst, cur, col2, E2);
    }

    const int gemm_blocks = (N + 63) / 64;
    const int node_blocks = (N + 3) / 4;

    const float* cur_x = x;
    for (int L = 0; L < 5; ++L) {
        gemm128<<<gemm_blocks, 256, 0, stream>>>(cur_x, W[L], Hbuf, N);
        alar_kernel<<<node_blocks, 256, 0, stream>>>(Hbuf, asv[L], adv[L], al, ar, N);
        const int* ro = (L % 2 == 0) ? ro1 : ro2;
        const int* co = (L % 2 == 0) ? col1 : col2;
        agg_kernel<<<node_blocks, 256, 0, stream>>>(Hbuf, al, ar, ro, co, bv[L], F, N,
                                                    (L < 4) ? 1 : 0);
        cur_x = F;
    }
}

// Round 2
// 773.431 us; speedup vs baseline: 1.5119x; 1.5119x over previous
//
#include <hip/hip_runtime.h>

#define DIM 128
#define NEG 0.2f

__device__ __forceinline__ float lrelu(float v) { return v > 0.f ? v : NEG * v; }

// ------------- GEMM + fused attention logits: H = X@W, al = H@a_src, ar = H@a_dst
// Block: 256 threads, tile 64 rows x 128 cols, full K=128.
// Thread t: cols c0..c0+3 (c0=(t&31)*4), rows rg..rg+7 (rg=(t>>5)*8).
__global__ __launch_bounds__(256) void gemm128_fused(const float* __restrict__ X,
                                                     const float* __restrict__ W,
                                                     const float* __restrict__ asrc,
                                                     const float* __restrict__ adst,
                                                     float* __restrict__ H,
                                                     float* __restrict__ al,
                                                     float* __restrict__ ar, int N) {
    __shared__ float sx[64 * 128];
    const int t = threadIdx.x;
    const int r0g = blockIdx.x * 64;
    const int remRows = N - r0g;

    // stage X tile (2048 float4s, 8 per thread)
    const float4* X4 = (const float4*)(X + (size_t)r0g * DIM);
    float4* sx4 = (float4*)sx;
#pragma unroll
    for (int i = 0; i < 8; ++i) {
        int f = t + i * 256;      // float4 index in tile
        int row = f >> 5;         // 32 float4 per row
        float4 v = make_float4(0.f, 0.f, 0.f, 0.f);
        if (row < remRows) v = X4[f];
        sx4[f] = v;
    }
    __syncthreads();

    const int c0 = (t & 31) * 4;
    const int rg = (t >> 5) * 8;
    float acc[8][4];
#pragma unroll
    for (int i = 0; i < 8; ++i)
#pragma unroll
        for (int j = 0; j < 4; ++j) acc[i][j] = 0.f;

    const float* Wp = W + c0;
    for (int k = 0; k < 128; k += 4) {
        float4 w0 = *(const float4*)(Wp + (k + 0) * DIM);
        float4 w1 = *(const float4*)(Wp + (k + 1) * DIM);
        float4 w2 = *(const float4*)(Wp + (k + 2) * DIM);
        float4 w3 = *(const float4*)(Wp + (k + 3) * DIM);
#pragma unroll
        for (int i = 0; i < 8; ++i) {
            float4 a = *(const float4*)(sx + (rg + i) * 128 + k);
            acc[i][0] += a.x * w0.x; acc[i][1] += a.x * w0.y; acc[i][2] += a.x * w0.z; acc[i][3] += a.x * w0.w;
            acc[i][0] += a.y * w1.x; acc[i][1] += a.y * w1.y; acc[i][2] += a.y * w1.z; acc[i][3] += a.y * w1.w;
            acc[i][0] += a.z * w2.x; acc[i][1] += a.z * w2.y; acc[i][2] += a.z * w2.z; acc[i][3] += a.z * w2.w;
            acc[i][0] += a.w * w3.x; acc[i][1] += a.w * w3.y; acc[i][2] += a.w * w3.z; acc[i][3] += a.w * w3.w;
        }
    }

#pragma unroll
    for (int i = 0; i < 8; ++i) {
        int row = rg + i;
        if (row < remRows) {
            float4 o = make_float4(acc[i][0], acc[i][1], acc[i][2], acc[i][3]);
            *(float4*)(H + (size_t)(r0g + row) * DIM + c0) = o;
        }
    }

    // ---- fused epilogue: al/ar via half-wave reduction (lanes sharing rg) ----
    float4 av = *(const float4*)(asrc + c0);
    float4 dv = *(const float4*)(adst + c0);
    float pa[8], pr[8];
#pragma unroll
    for (int i = 0; i < 8; ++i) {
        pa[i] = acc[i][0] * av.x + acc[i][1] * av.y + acc[i][2] * av.z + acc[i][3] * av.w;
        pr[i] = acc[i][0] * dv.x + acc[i][1] * dv.y + acc[i][2] * dv.z + acc[i][3] * dv.w;
    }
#pragma unroll
    for (int off = 16; off; off >>= 1) {
#pragma unroll
        for (int i = 0; i < 8; ++i) {
            pa[i] += __shfl_xor(pa[i], off);
            pr[i] += __shfl_xor(pr[i], off);
        }
    }
    if ((t & 31) == 0) {
#pragma unroll
        for (int i = 0; i < 8; ++i) {
            int row = rg + i;
            if (row < remRows) {
                al[r0g + row] = pa[i];
                ar[r0g + row] = pr[i];
            }
        }
    }
}

// ---------------- CSR build helpers ----------------
__global__ void hist_kernel(const int* __restrict__ dst, int* __restrict__ cnt, int E) {
    int e = blockIdx.x * blockDim.x + threadIdx.x;
    if (e < E) atomicAdd(&cnt[dst[e]], 1);
}

// k1: per-1024-block sums
__global__ __launch_bounds__(1024) void block_sum_kernel(const int* __restrict__ cnt,
                                                         int* __restrict__ bsum, int N) {
    __shared__ int wsum[16];
    int t = threadIdx.x, wave = t >> 6, lane = t & 63;
    int i = blockIdx.x * 1024 + t;
    int v = (i < N) ? cnt[i] : 0;
#pragma unroll
    for (int off = 32; off; off >>= 1) v += __shfl_xor(v, off);
    if (lane == 0) wsum[wave] = v;
    __syncthreads();
    if (t == 0) {
        int s = 0;
#pragma unroll
        for (int j = 0; j < 16; ++j) s += wsum[j];
        bsum[blockIdx.x] = s;
    }
}

// k2: one wave scans the (<=64) block sums in-place to exclusive offsets; total -> row_off[N]
__global__ __launch_bounds__(64) void scan_bsums_kernel(int* __restrict__ bsum, int nb,
                                                        int* __restrict__ row_off, int N) {
    int lane = threadIdx.x;
    int v = (lane < nb) ? bsum[lane] : 0;
    int s = v;
#pragma unroll
    for (int off = 1; off < 64; off <<= 1) {
        int tt = __shfl_up(s, off);
        if (lane >= off) s += tt;
    }
    if (lane < nb) bsum[lane] = s - v;  // exclusive
    if (lane == 63) row_off[N] = s;     // grand total
}

// k3: in-block scan + block offset -> row_off / cursor
__global__ __launch_bounds__(1024) void block_scan_kernel(const int* __restrict__ cnt,
                                                          const int* __restrict__ bsum,
                                                          int* __restrict__ row_off,
                                                          int* __restrict__ cursor, int N) {
    __shared__ int wsum[16];
    __shared__ int woff[16];
    int t = threadIdx.x, wave = t >> 6, lane = t & 63;
    int i = blockIdx.x * 1024 + t;
    int v = (i < N) ? cnt[i] : 0;
    int s = v;
#pragma unroll
    for (int off = 1; off < 64; off <<= 1) {
        int tt = __shfl_up(s, off);
        if (lane >= off) s += tt;
    }
    if (lane == 63) wsum[wave] = s;
    __syncthreads();
    if (t == 0) {
        int r = 0;
#pragma unroll
        for (int j = 0; j < 16; ++j) { woff[j] = r; r += wsum[j]; }
    }
    __syncthreads();
    if (i < N) {
        int excl = bsum[blockIdx.x] + woff[wave] + s - v;
        row_off[i] = excl;
        cursor[i] = excl;
    }
}

__global__ void scatter_kernel(const int* __restrict__ src, const int* __restrict__ dst,
                               int* __restrict__ cursor, int* __restrict__ col, int E) {
    int e = blockIdx.x * blockDim.x + threadIdx.x;
    if (e < E) {
        int d = dst[e];
        int p = atomicAdd(&cursor[d], 1);
        col[p] = src[e];
    }
}

// ---------------- fused softmax-by-dst + aggregation, one wave per node -----
// Phase A: online softmax (single gather pass, 64 lanes strided).
// Phase B: 2 half-waves (32 lanes x float4 = 128 dims) process alternate edges,
//          unrolled x2 -> 4 independent 512B row loads in flight per wave.
__global__ __launch_bounds__(256) void agg_kernel(const float* __restrict__ H,
                                                  const float* __restrict__ al,
                                                  const float* __restrict__ ar,
                                                  const int* __restrict__ row_off,
                                                  const int* __restrict__ col,
                                                  const float* __restrict__ bias,
                                                  float* __restrict__ out, int N, int relu) {
    int w = blockIdx.x * 4 + (threadIdx.x >> 6);
    int lane = threadIdx.x & 63;
    if (w >= N) return;

    const int beg = row_off[w], end = row_off[w + 1];
    const float arn = ar[w];
    const float vself = lrelu(al[w] + arn);

    // ---- phase A: online segment softmax (max+sum in one pass) ----
    const float NEGBIG = -1e30f;  // finite sentinel: avoids -inf - -inf = NaN in merge
    float mm = NEGBIG, ss = 0.f;
    for (int e = beg + lane; e < end; e += 64) {
        float v = lrelu(al[col[e]] + arn);
        float nm = fmaxf(mm, v);
        ss = ss * __expf(mm - nm) + __expf(v - nm);
        mm = nm;
    }
#pragma unroll
    for (int off = 32; off; off >>= 1) {
        float mo = __shfl_xor(mm, off);
        float so = __shfl_xor(ss, off);
        float nm = fmaxf(mm, mo);
        ss = ss * __expf(mm - nm) + so * __expf(mo - nm);
        mm = nm;
    }
    {   // merge self-loop term
        float nm = fmaxf(mm, vself);
        ss = ss * __expf(mm - nm) + __expf(vself - nm);
        mm = nm;
    }
    const float m = mm;
    const float invs = 1.f / ss;

    // ---- phase B: weighted aggregation, 2 edges in parallel + unroll 2 ----
    const int half = lane >> 5;
    const int l32 = lane & 31;
    const float aself = __expf(vself - m) * invs;
    float4 hs = *(const float4*)(H + (size_t)w * DIM + 4 * l32);
    float4 acc;
    if (half == 0) {
        acc = make_float4(aself * hs.x, aself * hs.y, aself * hs.z, aself * hs.w);
    } else {
        acc = make_float4(0.f, 0.f, 0.f, 0.f);
    }

    int e = beg + half;
    for (; e + 2 < end; e += 4) {
        int sn0 = col[e];
        int sn1 = col[e + 2];
        float al0 = al[sn0];
        float al1 = al[sn1];
        float4 h0 = *(const float4*)(H + (size_t)sn0 * DIM + 4 * l32);
        float4 h1 = *(const float4*)(H + (size_t)sn1 * DIM + 4 * l32);
        float a0 = __expf(lrelu(al0 + arn) - m) * invs;
        float a1 = __expf(lrelu(al1 + arn) - m) * invs;
        acc.x += a0 * h0.x + a1 * h1.x;
        acc.y += a0 * h0.y + a1 * h1.y;
        acc.z += a0 * h0.z + a1 * h1.z;
        acc.w += a0 * h0.w + a1 * h1.w;
    }
    for (; e < end; e += 2) {
        int sn = col[e];
        float a0 = __expf(lrelu(al[sn] + arn) - m) * invs;
        float4 hv = *(const float4*)(H + (size_t)sn * DIM + 4 * l32);
        acc.x += a0 * hv.x;
        acc.y += a0 * hv.y;
        acc.z += a0 * hv.z;
        acc.w += a0 * hv.w;
    }

    // combine halves
    acc.x += __shfl_xor(acc.x, 32);
    acc.y += __shfl_xor(acc.y, 32);
    acc.z += __shfl_xor(acc.z, 32);
    acc.w += __shfl_xor(acc.w, 32);

    if (half == 0) {
        float4 b = *(const float4*)(bias + 4 * l32);
        float4 o = make_float4(acc.x + b.x, acc.y + b.y, acc.z + b.z, acc.w + b.w);
        if (relu) {
            o.x = fmaxf(o.x, 0.f); o.y = fmaxf(o.y, 0.f);
            o.z = fmaxf(o.z, 0.f); o.w = fmaxf(o.w, 0.f);
        }
        *(float4*)(out + (size_t)w * DIM + 4 * l32) = o;
    }
}

// ---------------- host-side launch ----------------
extern "C" void kernel_launch(void* const* d_in, const int* in_sizes, int n_in,
                              void* d_out, int out_size, void* d_ws, size_t ws_size,
                              hipStream_t stream) {
    const float* x = (const float*)d_in[0];
    const float* W[5];
    const float* asv[5];
    const float* adv[5];
    const float* bv[5];
    for (int i = 0; i < 5; ++i) {
        W[i]   = (const float*)d_in[1 + 4 * i];
        asv[i] = (const float*)d_in[2 + 4 * i];
        adv[i] = (const float*)d_in[3 + 4 * i];
        bv[i]  = (const float*)d_in[4 + 4 * i];
    }
    const int* ei  = (const int*)d_in[21];
    const int* eix = (const int*)d_in[22];
    const int N  = in_sizes[0] / DIM;
    const int E1 = in_sizes[21] / 2;
    const int E2 = in_sizes[22] / 2;

    // workspace layout
    size_t off = 0;
    auto alloc = [&](size_t bytes) {
        void* r = (char*)d_ws + off;
        off += (bytes + 255) & ~(size_t)255;
        return r;
    };
    float* Hbuf = (float*)alloc((size_t)N * DIM * sizeof(float));
    float* al   = (float*)alloc((size_t)N * sizeof(float));
    float* ar   = (float*)alloc((size_t)N * sizeof(float));
    int* cnt    = (int*)alloc((size_t)N * sizeof(int));
    int* cur    = (int*)alloc((size_t)N * sizeof(int));
    int* bsum   = (int*)alloc(64 * sizeof(int));
    int* ro1    = (int*)alloc((size_t)(N + 1) * sizeof(int));
    int* col1   = (int*)alloc((size_t)E1 * sizeof(int));
    int* ro2    = (int*)alloc((size_t)(N + 1) * sizeof(int));
    int* col2   = (int*)alloc((size_t)E2 * sizeof(int));
    (void)ws_size;

    float* F = (float*)d_out;  // feature ping-pong lives in d_out

    const int nb = (N + 1023) / 1024;  // <= 64 for N <= 65536

    // build CSR (by dst) for both edge sets
    {
        const int* src = ei;
        const int* dst = ei + E1;
        hipMemsetAsync(cnt, 0, (size_t)N * sizeof(int), stream);
        hist_kernel<<<(E1 + 255) / 256, 256, 0, stream>>>(dst, cnt, E1);
        block_sum_kernel<<<nb, 1024, 0, stream>>>(cnt, bsum, N);
        scan_bsums_kernel<<<1, 64, 0, stream>>>(bsum, nb, ro1, N);
        block_scan_kernel<<<nb, 1024, 0, stream>>>(cnt, bsum, ro1, cur, N);
        scatter_kernel<<<(E1 + 255) / 256, 256, 0, stream>>>(src, dst, cur, col1, E1);
    }
    {
        const int* src = eix;
        const int* dst = eix + E2;
        hipMemsetAsync(cnt, 0, (size_t)N * sizeof(int), stream);
        hist_kernel<<<(E2 + 255) / 256, 256, 0, stream>>>(dst, cnt, E2);
        block_sum_kernel<<<nb, 1024, 0, stream>>>(cnt, bsum, N);
        scan_bsums_kernel<<<1, 64, 0, stream>>>(bsum, nb, ro2, N);
        block_scan_kernel<<<nb, 1024, 0, stream>>>(cnt, bsum, ro2, cur, N);
        scatter_kernel<<<(E2 + 255) / 256, 256, 0, stream>>>(src, dst, cur, col2, E2);
    }

    const int gemm_blocks = (N + 63) / 64;
    const int node_blocks = (N + 3) / 4;

    const float* cur_x = x;
    for (int L = 0; L < 5; ++L) {
        gemm128_fused<<<gemm_blocks, 256, 0, stream>>>(cur_x, W[L], asv[L], adv[L],
                                                       Hbuf, al, ar, N);
        const int* ro = (L % 2 == 0) ? ro1 : ro2;
        const int* co = (L % 2 == 0) ? col1 : col2;
        agg_kernel<<<node_blocks, 256, 0, stream>>>(Hbuf, al, ar, ro, co, bv[L], F, N,
                                                    (L < 4) ? 1 : 0);
        cur_x = F;
    }
}